// Round 11
// baseline (10149.422 us; speedup 1.0000x reference)
//
#include <hip/hip_runtime.h>

#define Bb 32
#define Tt 512
#define Ee 512
#define Hh 1024
#define NSLOT 256

typedef __attribute__((ext_vector_type(8))) short bf16x8;
typedef __attribute__((ext_vector_type(4))) float f32x4;
typedef unsigned long long u64;

__device__ __forceinline__ unsigned short f2bf(float f) {
  unsigned int u = __float_as_uint(f);
  u = (u + 0x7fffu + ((u >> 16) & 1u)) >> 16;
  return (unsigned short)u;
}
__device__ __forceinline__ float bf2f(unsigned short s) {
  return __uint_as_float(((unsigned int)s) << 16);
}
__device__ __forceinline__ float sigmoidf_(float x) {
  x = fminf(fmaxf(x, -30.f), 30.f);
  return 1.f / (1.f + __expf(-x));
}
__device__ __forceinline__ float tanh_fast(float x) {
  float xx = fminf(fmaxf(x, -15.f), 15.f);
  float e = __expf(2.f * xx);
  return (e - 1.f) / (e + 1.f);
}

// K1: gather embedding rows -> bf16 hi/lo; zero h ring slot 0 + flag state.
__global__ void gather_kernel(const int* __restrict__ x,
                              const float* __restrict__ emb,
                              unsigned short* __restrict__ emb_hi,
                              unsigned short* __restrict__ emb_lo,
                              unsigned short* __restrict__ hbuf,
                              unsigned* __restrict__ bar) {
  long long gid = (long long)blockIdx.x * blockDim.x + threadIdx.x;
  long long stride = (long long)gridDim.x * blockDim.x;
  for (long long i = gid; i < 8192; i += stride)
    ((ushort4*)hbuf)[i] = make_ushort4(0, 0, 0, 0);
  for (long long i = gid; i < 1024; i += stride)
    bar[i] = 0u;
  long long n4 = (long long)Bb * Tt * Ee / 4;
  for (long long i = gid; i < n4; i += stride) {
    long long bt = i >> 7;
    int e4 = (int)(i & 127);
    int row = x[bt];
    row = min(max(row, 0), 31999);
    float4 v = ((const float4*)(emb + (long long)row * Ee))[e4];
    ushort4 hv, lv;
    hv.x = f2bf(v.x); lv.x = f2bf(v.x - bf2f(hv.x));
    hv.y = f2bf(v.y); lv.y = f2bf(v.y - bf2f(hv.y));
    hv.z = f2bf(v.z); lv.z = f2bf(v.z - bf2f(hv.z));
    hv.w = f2bf(v.w); lv.w = f2bf(v.w - bf2f(hv.w));
    ((ushort4*)emb_hi)[i] = hv;
    ((ushort4*)emb_lo)[i] = lv;
  }
}

// K2: persistent LSTM, ONE 64-lane wave per WG (no barriers in the loop).
// gates^T = W·h^T via mfma(W_frag, h_frag, acc): same load patterns as the
// proven kernel, swapped operand order. C/D: col=lane&15=batch,
// row=(lane>>4)*4+r = gate-slice row c = gate*4+du -> member g holds gate g,
// unit r. 4x4 cross-lane transpose (xor 32 then 16) gives lane (b, du=lane>>4)
// all four gates. c-state in registers. Publish via LDS staging -> 32
// coalesced 8B sc1 stores; ONE flag add per WG; poll with lanes<32.
__global__ __launch_bounds__(64, 1)
void lstm_kernel(const unsigned short* __restrict__ emb_hi,
                 const unsigned short* __restrict__ emb_lo,
                 unsigned short* __restrict__ hbuf,
                 unsigned* __restrict__ bar,
                 const float* __restrict__ W_ih,
                 const float* __restrict__ W_hh,
                 const float* __restrict__ b_ih,
                 const float* __restrict__ b_hh,
                 float* __restrict__ out) {
  __shared__ unsigned short sWih_hi[16 * 512];
  __shared__ unsigned short sWih_lo[16 * 512];
  __shared__ unsigned short sWhh_hi[16 * 1024];
  __shared__ unsigned short sWhh_lo[16 * 1024];
  __shared__ unsigned short sHpub[32][4];   // bf16 publish staging
  __shared__ float sHout[32][4];            // f32 out staging

  const int tid = threadIdx.x;              // == lane
  const int wg = blockIdx.x;
  const int j0 = (wg & 7) * 128 + (wg >> 3) * 4;
  const int gflag = (wg & 7) * 4 + (wg >> 6);

  // ---- stage W_ih slice (16 rows x 512) hi/lo bf16, XOR-swizzled ----
  for (int idx = tid; idx < 16 * 64; idx += 64) {
    int c = idx >> 6, kc8 = idx & 63;
    int grow = (c >> 2) * Hh + j0 + (c & 3);
    const float* src = W_ih + (long long)grow * Ee + kc8 * 8;
    int us = (c * 512 + kc8 * 8) ^ ((c & 7) << 3);
#pragma unroll
    for (int j = 0; j < 8; j++) {
      float f = src[j];
      unsigned short h = f2bf(f);
      sWih_hi[us + j] = h;
      sWih_lo[us + j] = f2bf(f - bf2f(h));
    }
  }
  // ---- stage W_hh slice (16 rows x 1024) ----
  for (int idx = tid; idx < 16 * 128; idx += 64) {
    int c = idx >> 7, kc8 = idx & 127;
    int grow = (c >> 2) * Hh + j0 + (c & 3);
    const float* src = W_hh + (long long)grow * Hh + kc8 * 8;
    int us = (c * 1024 + kc8 * 8) ^ ((c & 7) << 3);
#pragma unroll
    for (int j = 0; j < 8; j++) {
      float f = src[j];
      unsigned short h = f2bf(f);
      sWhh_hi[us + j] = h;
      sWhh_lo[us + j] = f2bf(f - bf2f(h));
    }
  }

  const int b0 = tid & 15;          // batch (tile-local) = MFMA col
  const int du = tid >> 4;          // this lane's unit after transpose
  const int kg = (tid >> 4) * 8;    // k-offset within 32-chunk
  const int cW = tid & 15;          // W gate-slice row for A-frag
  const int xr = (cW & 7) << 3;     // LDS swizzle

  // per-lane bias: gates 0..3 of unit du
  float bias_g[4];
#pragma unroll
  for (int g = 0; g < 4; g++)
    bias_g[g] = b_ih[g * Hh + j0 + du] + b_hh[g * Hh + j0 + du];

  float c_reg[2] = {0.f, 0.f};
  float hL[2] = {0.f, 0.f}, cL[2] = {0.f, 0.f};

  f32x4 xacc[2][3];
  auto xproj = [&](int t) {
#pragma unroll
    for (int mt = 0; mt < 2; mt++)
#pragma unroll
      for (int cb = 0; cb < 3; cb++)
        xacc[mt][cb] = (f32x4){0.f, 0.f, 0.f, 0.f};
#pragma unroll
    for (int q = 0; q < 16; q++) {
      int bo = (cW * 512 + q * 32 + kg) ^ xr;
      bf16x8 wH = *(const bf16x8*)(sWih_hi + bo);
      bf16x8 wL = *(const bf16x8*)(sWih_lo + bo);
#pragma unroll
      for (int mt = 0; mt < 2; mt++) {
        long long ai = ((long long)(mt * 16 + b0) * Tt + t) * Ee + q * 32 + kg;
        bf16x8 eH = *(const bf16x8*)(emb_hi + ai);
        bf16x8 eL = *(const bf16x8*)(emb_lo + ai);
        xacc[mt][0] = __builtin_amdgcn_mfma_f32_16x16x32_bf16(wH, eH, xacc[mt][0], 0, 0, 0);
        xacc[mt][1] = __builtin_amdgcn_mfma_f32_16x16x32_bf16(wL, eH, xacc[mt][1], 0, 0, 0);
        xacc[mt][2] = __builtin_amdgcn_mfma_f32_16x16x32_bf16(wH, eL, xacc[mt][2], 0, 0, 0);
      }
    }
  };
  xproj(0);

  for (int t = 0; t < Tt; t++) {
    // ---- wait: all 32 flag lines reached 8*t (h[t] fully at LLC) ----
    {
      unsigned tgt = 8u * (unsigned)t;
      for (;;) {
        unsigned v = tgt;
        if (tid < 32)
          v = __hip_atomic_load(bar + (unsigned)tid * 16, __ATOMIC_RELAXED,
                                __HIP_MEMORY_SCOPE_AGENT);
        if (!__any(v < tgt)) break;
        __builtin_amdgcn_s_sleep(1);
      }
    }
    __builtin_amdgcn_sched_barrier(0);

    // ---- recurrent MFMAs: full K in this wave, h from cold ring slot ----
    const unsigned short* hb = hbuf + (unsigned)(t & (NSLOT - 1)) * 32768;
    f32x4 racc[2][2];
#pragma unroll
    for (int mt = 0; mt < 2; mt++) {
      racc[mt][0] = xacc[mt][0] + xacc[mt][2];
      racc[mt][1] = xacc[mt][1];
    }
#pragma unroll
    for (int q = 0; q < 32; q++) {
      int bo = (cW * 1024 + q * 32 + kg) ^ xr;
      bf16x8 wH = *(const bf16x8*)(sWhh_hi + bo);
      bf16x8 wL = *(const bf16x8*)(sWhh_lo + bo);
#pragma unroll
      for (int mt = 0; mt < 2; mt++) {
        bf16x8 hf = *(const bf16x8*)(hb + (b0 + 16 * mt) * 1024 + q * 32 + kg);
        racc[mt][0] = __builtin_amdgcn_mfma_f32_16x16x32_bf16(wH, hf, racc[mt][0], 0, 0, 0);
        racc[mt][1] = __builtin_amdgcn_mfma_f32_16x16x32_bf16(wL, hf, racc[mt][1], 0, 0, 0);
      }
    }

    // ---- per-tile: 4x4 cross-lane transpose + cell (register-only) ----
#pragma unroll
    for (int mt = 0; mt < 2; mt++) {
      f32x4 v = racc[mt][0] + racc[mt][1];
      float r0 = v[0], r1 = v[1], r2 = v[2], r3 = v[3];
      float p0 = __shfl_xor(r0, 32), p1 = __shfl_xor(r1, 32);
      float p2 = __shfl_xor(r2, 32), p3 = __shfl_xor(r3, 32);
      bool lowg = (tid & 32) == 0;
      float n0 = lowg ? r0 : p2, n1 = lowg ? r1 : p3;
      float n2 = lowg ? p0 : r2, n3 = lowg ? p1 : r3;
      float q0 = __shfl_xor(n0, 16), q1 = __shfl_xor(n1, 16);
      float q2 = __shfl_xor(n2, 16), q3 = __shfl_xor(n3, 16);
      bool eg = (tid & 16) == 0;
      float gi = eg ? n0 : q1;   // gate i for (b, du)
      float gf = eg ? q0 : n1;   // gate f
      float gg = eg ? n2 : q3;   // gate g
      float go = eg ? q2 : n3;   // gate o
      float i_ = sigmoidf_(gi + bias_g[0]);
      float f_ = sigmoidf_(gf + bias_g[1]);
      float g_ = tanh_fast(gg + bias_g[2]);
      float o_ = sigmoidf_(go + bias_g[3]);
      float cn = f_ * c_reg[mt] + i_ * g_;
      c_reg[mt] = cn;
      float hn = o_ * tanh_fast(cn);
      hL[mt] = hn; cL[mt] = cn;
      int bg = b0 + 16 * mt;
      sHpub[bg][du] = f2bf(hn);
      sHout[bg][du] = hn;
    }

    // ---- publish: 32 coalesced 8B sc1 stores, drain, ONE flag add ----
    if (tid < 32) {
      u64 w = *(const u64*)&sHpub[tid][0];
      u64* dst = (u64*)(hbuf + (unsigned)((t + 1) & (NSLOT - 1)) * 32768 +
                        tid * 1024 + j0);
      __hip_atomic_store(dst, w, __ATOMIC_RELAXED, __HIP_MEMORY_SCOPE_AGENT);
    }
    asm volatile("s_waitcnt vmcnt(0)" ::: "memory");
    if (tid == 0)
      __hip_atomic_fetch_add(bar + gflag * 16, 1u, __ATOMIC_RELAXED,
                             __HIP_MEMORY_SCOPE_AGENT);

    // ---- out stores (off publish path): 32 coalesced 16B stores ----
    if (tid < 32) {
      float4 vv = *(const float4*)&sHout[tid][0];
      *(float4*)(out + ((long long)tid * Tt + t) * Hh + j0) = vv;
    }

    // ---- x_proj for t+1 fills the inter-step wait ----
    if (t + 1 < Tt) xproj(t + 1);
  }

  // ---- final states via the same staging ----
  sHout[b0][du] = hL[0];
  sHout[b0 + 16][du] = hL[1];
  if (tid < 32) {
    float4 vv = *(const float4*)&sHout[tid][0];
    *(float4*)(out + 16777216LL + (long long)tid * Hh + j0) = vv;
  }
  __builtin_amdgcn_sched_barrier(0);
  sHout[b0][du] = cL[0];
  sHout[b0 + 16][du] = cL[1];
  if (tid < 32) {
    float4 vv = *(const float4*)&sHout[tid][0];
    *(float4*)(out + 16777216LL + 32768 + (long long)tid * Hh + j0) = vv;
  }
}

extern "C" void kernel_launch(void* const* d_in, const int* in_sizes, int n_in,
                              void* d_out, int out_size, void* d_ws, size_t ws_size,
                              hipStream_t stream) {
  const int* x      = (const int*)d_in[0];
  const float* emb  = (const float*)d_in[1];
  const float* W_ih = (const float*)d_in[2];
  const float* W_hh = (const float*)d_in[3];
  const float* b_ih = (const float*)d_in[4];
  const float* b_hh = (const float*)d_in[5];
  float* out = (float*)d_out;

  unsigned short* emb_hi = (unsigned short*)d_ws;      // 16 MB
  unsigned short* emb_lo = emb_hi + 8388608;           // 16 MB
  unsigned short* hbuf   = emb_lo + 8388608;           // 256-slot ring, 16 MB
  unsigned*       bar    = (unsigned*)(hbuf + 8388608); // 4 KB flag state

  hipLaunchKernelGGL(gather_kernel, dim3(2048), dim3(256), 0, stream,
                     x, emb, emb_hi, emb_lo, hbuf, bar);

  void* args[] = { (void*)&emb_hi, (void*)&emb_lo, (void*)&hbuf, (void*)&bar,
                   (void*)&W_ih, (void*)&W_hh, (void*)&b_ih, (void*)&b_hh,
                   (void*)&out };
  hipLaunchCooperativeKernel((void*)lstm_kernel, dim3(256), dim3(64), args, 0, stream);
}

// Round 12
// 3852.565 us; speedup vs baseline: 2.6345x; 2.6345x over previous
//
#include <hip/hip_runtime.h>

#define Bb 32
#define Tt 512
#define Ee 512
#define Hh 1024

typedef __attribute__((ext_vector_type(8))) short bf16x8;
typedef __attribute__((ext_vector_type(4))) float f32x4;
typedef unsigned long long u64;

#define SEN 0x7FC0u   // bf16 NaN sentinel; f2bf(finite) can never produce it

__device__ __forceinline__ unsigned short f2bf(float f) {
  unsigned int u = __float_as_uint(f);
  u = (u + 0x7fffu + ((u >> 16) & 1u)) >> 16;
  return (unsigned short)u;
}
__device__ __forceinline__ float bf2f(unsigned short s) {
  return __uint_as_float(((unsigned int)s) << 16);
}
__device__ __forceinline__ float sigmoidf_(float x) {
  x = fminf(fmaxf(x, -30.f), 30.f);
  return 1.f / (1.f + __expf(-x));
}
__device__ __forceinline__ float tanh_fast(float x) {
  float xx = fminf(fmaxf(x, -15.f), 15.f);
  float e = __expf(2.f * xx);
  return (e - 1.f) / (e + 1.f);
}

// K1: gather embedding rows -> bf16 hi/lo; ring slot0 = zeros (h0),
// slots 1..511 = NaN sentinel (not-yet-published marker).
__global__ void gather_kernel(const int* __restrict__ x,
                              const float* __restrict__ emb,
                              unsigned short* __restrict__ emb_hi,
                              unsigned short* __restrict__ emb_lo,
                              unsigned short* __restrict__ hbuf) {
  long long gid = (long long)blockIdx.x * blockDim.x + threadIdx.x;
  long long stride = (long long)gridDim.x * blockDim.x;
  // slot 0: 8192 ushort4 of zeros
  for (long long i = gid; i < 8192; i += stride)
    ((ushort4*)hbuf)[i] = make_ushort4(0, 0, 0, 0);
  // slots 1..511: sentinel fill (512*8192 = 4194304 ushort4 total)
  for (long long i = 8192 + gid; i < 4194304; i += stride)
    ((ushort4*)hbuf)[i] =
        make_ushort4((unsigned short)SEN, (unsigned short)SEN,
                     (unsigned short)SEN, (unsigned short)SEN);
  long long n4 = (long long)Bb * Tt * Ee / 4;
  for (long long i = gid; i < n4; i += stride) {
    long long bt = i >> 7;
    int e4 = (int)(i & 127);
    int row = x[bt];
    row = min(max(row, 0), 31999);
    float4 v = ((const float4*)(emb + (long long)row * Ee))[e4];
    ushort4 hv, lv;
    hv.x = f2bf(v.x); lv.x = f2bf(v.x - bf2f(hv.x));
    hv.y = f2bf(v.y); lv.y = f2bf(v.y - bf2f(hv.y));
    hv.z = f2bf(v.z); lv.z = f2bf(v.z - bf2f(hv.z));
    hv.w = f2bf(v.w); lv.w = f2bf(v.w - bf2f(hv.w));
    ((ushort4*)emb_hi)[i] = hv;
    ((ushort4*)emb_lo)[i] = lv;
  }
}

// K2: persistent LSTM, 256 WGs x 4 waves (R9 structure), FLAGLESS dataflow:
// producers publish h[t+1] as atomic 8B sc1 words (4 bf16 each) into slot
// t+1 of a 512-slot no-reuse ring; consumers spin on the words themselves
// (NaN low-half = not ready). No flags, no fences, no drains in the loop.
__global__ __launch_bounds__(256, 1)
void lstm_kernel(const unsigned short* __restrict__ emb_hi,
                 const unsigned short* __restrict__ emb_lo,
                 unsigned short* __restrict__ hbuf,
                 const float* __restrict__ W_ih,
                 const float* __restrict__ W_hh,
                 const float* __restrict__ b_ih,
                 const float* __restrict__ b_hh,
                 float* __restrict__ out) {
  __shared__ unsigned short sWih_hi[16 * 512];
  __shared__ unsigned short sWih_lo[16 * 512];
  __shared__ unsigned short sWhh_hi[16 * 1024];
  __shared__ unsigned short sWhh_lo[16 * 1024];
  __shared__ float sAcc[2][4][2][16][17];
  __shared__ float sBias[16];
  __shared__ float sC[32][4];

  const int tid = threadIdx.x;
  const int lane = tid & 63;
  const int wv = tid >> 6;
  const int wg = blockIdx.x;
  const int j0 = (wg & 7) * 128 + (wg >> 3) * 4;

  // ---- stage W_ih slice (16 rows x 512) hi/lo bf16, XOR-swizzled ----
  for (int idx = tid; idx < 16 * 64; idx += 256) {
    int c = idx >> 6, kc8 = idx & 63;
    int grow = (c >> 2) * Hh + j0 + (c & 3);
    const float* src = W_ih + (long long)grow * Ee + kc8 * 8;
    int us = (c * 512 + kc8 * 8) ^ ((c & 7) << 3);
#pragma unroll
    for (int j = 0; j < 8; j++) {
      float f = src[j];
      unsigned short h = f2bf(f);
      sWih_hi[us + j] = h;
      sWih_lo[us + j] = f2bf(f - bf2f(h));
    }
  }
  // ---- stage W_hh slice (16 rows x 1024) ----
  for (int idx = tid; idx < 16 * 128; idx += 256) {
    int c = idx >> 7, kc8 = idx & 127;
    int grow = (c >> 2) * Hh + j0 + (c & 3);
    const float* src = W_hh + (long long)grow * Hh + kc8 * 8;
    int us = (c * 1024 + kc8 * 8) ^ ((c & 7) << 3);
#pragma unroll
    for (int j = 0; j < 8; j++) {
      float f = src[j];
      unsigned short h = f2bf(f);
      sWhh_hi[us + j] = h;
      sWhh_lo[us + j] = f2bf(f - bf2f(h));
    }
  }
  if (tid < 16) {
    int grow = (tid >> 2) * Hh + j0 + (tid & 3);
    sBias[tid] = b_ih[grow] + b_hh[grow];
  }
  if (tid < 128) sC[tid >> 2][tid & 3] = 0.f;
  __syncthreads();

  const int r16 = lane & 15;        // A-frag row (batch)
  const int kg = (lane >> 4) * 8;   // k-offset in 32-chunk
  const int kgq = (lane >> 4) * 2;  // same, in u64 units
  const int col = lane & 15;        // B-frag col = gate-slice row
  const int xr = (col & 7) << 3;    // LDS swizzle

  float h_last = 0.f, c_last = 0.f;

  for (int t = 0; t < Tt; t++) {
    f32x4 acc[2][3];
#pragma unroll
    for (int mt = 0; mt < 2; mt++)
#pragma unroll
      for (int cb = 0; cb < 3; cb++)
        acc[mt][cb] = (f32x4){0.f, 0.f, 0.f, 0.f};

    // ---- x_proj contribution (independent of h; fills pre-publish time) ----
#pragma unroll
    for (int q = 0; q < 4; q++) {
      int kc = wv + q * 4;
      int bo = (col * 512 + kc * 32 + kg) ^ xr;
      bf16x8 bH = *(const bf16x8*)(sWih_hi + bo);
      bf16x8 bL = *(const bf16x8*)(sWih_lo + bo);
#pragma unroll
      for (int mt = 0; mt < 2; mt++) {
        int rb = mt * 16 + r16;
        int ai = (rb * Tt + t) * Ee + kc * 32 + kg;
        bf16x8 aH = *(const bf16x8*)(emb_hi + ai);
        bf16x8 aL = *(const bf16x8*)(emb_lo + ai);
        acc[mt][0] = __builtin_amdgcn_mfma_f32_16x16x32_bf16(aH, bH, acc[mt][0], 0, 0, 0);
        acc[mt][1] = __builtin_amdgcn_mfma_f32_16x16x32_bf16(aH, bL, acc[mt][1], 0, 0, 0);
        acc[mt][2] = __builtin_amdgcn_mfma_f32_16x16x32_bf16(aL, bH, acc[mt][2], 0, 0, 0);
      }
    }

    // ---- recurrent: poll the h words themselves (sentinel = not ready) ----
    const u64* hb64 = (const u64*)hbuf + (u64)t * 8192;
#pragma unroll
    for (int q = 0; q < 8; q++) {
      int kc = wv + q * 4;
      int i0 = r16 * 256 + kc * 8 + kgq;          // mt=0 fragment (2 u64)
      int i1 = (16 + r16) * 256 + kc * 8 + kgq;   // mt=1 fragment
      u64 a0, a1, c0, c1;
      for (;;) {
        a0 = __hip_atomic_load(hb64 + i0, __ATOMIC_RELAXED, __HIP_MEMORY_SCOPE_AGENT);
        a1 = __hip_atomic_load(hb64 + i0 + 1, __ATOMIC_RELAXED, __HIP_MEMORY_SCOPE_AGENT);
        c0 = __hip_atomic_load(hb64 + i1, __ATOMIC_RELAXED, __HIP_MEMORY_SCOPE_AGENT);
        c1 = __hip_atomic_load(hb64 + i1 + 1, __ATOMIC_RELAXED, __HIP_MEMORY_SCOPE_AGENT);
        bool bad = ((unsigned)(a0 & 0xFFFFu) == SEN) |
                   ((unsigned)(a1 & 0xFFFFu) == SEN) |
                   ((unsigned)(c0 & 0xFFFFu) == SEN) |
                   ((unsigned)(c1 & 0xFFFFu) == SEN);
        if (!__any(bad)) break;
      }
      union { u64 q2[2]; bf16x8 v; } ua, uc;
      ua.q2[0] = a0; ua.q2[1] = a1;
      uc.q2[0] = c0; uc.q2[1] = c1;
      int bo = (col * 1024 + kc * 32 + kg) ^ xr;
      bf16x8 bH = *(const bf16x8*)(sWhh_hi + bo);
      bf16x8 bL = *(const bf16x8*)(sWhh_lo + bo);
      acc[0][0] = __builtin_amdgcn_mfma_f32_16x16x32_bf16(ua.v, bH, acc[0][0], 0, 0, 0);
      acc[0][1] = __builtin_amdgcn_mfma_f32_16x16x32_bf16(ua.v, bL, acc[0][1], 0, 0, 0);
      acc[1][0] = __builtin_amdgcn_mfma_f32_16x16x32_bf16(uc.v, bH, acc[1][0], 0, 0, 0);
      acc[1][1] = __builtin_amdgcn_mfma_f32_16x16x32_bf16(uc.v, bL, acc[1][1], 0, 0, 0);
    }

    // ---- cross-wave K-split reduction via LDS (parity-double-buffered) ----
#pragma unroll
    for (int mt = 0; mt < 2; mt++) {
      f32x4 tot = acc[mt][0] + acc[mt][1] + acc[mt][2];
#pragma unroll
      for (int r = 0; r < 4; r++)
        sAcc[t & 1][wv][mt][(lane >> 4) * 4 + r][col] = tot[r];
    }
    __syncthreads();

    if (tid < 128) {
      int b = tid >> 2, du = tid & 3;
      int mt = b >> 4, rr = b & 15;
      float g0 = sBias[0 * 4 + du], g1 = sBias[1 * 4 + du];
      float g2 = sBias[2 * 4 + du], g3 = sBias[3 * 4 + du];
#pragma unroll
      for (int w = 0; w < 4; w++) {
        g0 += sAcc[t & 1][w][mt][rr][0 * 4 + du];
        g1 += sAcc[t & 1][w][mt][rr][1 * 4 + du];
        g2 += sAcc[t & 1][w][mt][rr][2 * 4 + du];
        g3 += sAcc[t & 1][w][mt][rr][3 * 4 + du];
      }
      float ig = sigmoidf_(g0);
      float fg = sigmoidf_(g1);
      float gg = tanh_fast(g2);
      float og = sigmoidf_(g3);
      float cn = fg * sC[b][du] + ig * gg;
      sC[b][du] = cn;
      float hn = og * tanh_fast(cn);
      h_last = hn; c_last = cn;

      // publish h[t+1]: pack 4 units into one u64 (shfl tree), ONE sc1 store
      unsigned p16 = (unsigned)f2bf(hn);
      unsigned o1 = __shfl_xor(p16, 1, 64);
      unsigned v32 = ((du & 1) == 0) ? ((p16 & 0xffffu) | (o1 << 16))
                                     : (((o1 & 0xffffu)) | (p16 << 16));
      unsigned o2 = __shfl_xor(v32, 2, 64);
      if (t + 1 < Tt && du == 0) {
        u64 w = (u64)v32 | ((u64)o2 << 32);
        u64* dst = (u64*)hbuf + (u64)(t + 1) * 8192 + b * 256 + (j0 >> 2);
        __hip_atomic_store(dst, w, __ATOMIC_RELAXED, __HIP_MEMORY_SCOPE_AGENT);
      }
      out[((long long)b * Tt + t) * Hh + j0 + du] = hn;
    }
    // no tail barrier: sAcc parity-buffered; ring slots never reused
  }

  if (tid < 128) {
    int b = tid >> 2, du = tid & 3;
    int hj = j0 + du;
    out[16777216LL + b * Hh + hj] = h_last;           // state_h
    out[16777216LL + 32768 + b * Hh + hj] = c_last;   // state_c
  }
}

extern "C" void kernel_launch(void* const* d_in, const int* in_sizes, int n_in,
                              void* d_out, int out_size, void* d_ws, size_t ws_size,
                              hipStream_t stream) {
  const int* x      = (const int*)d_in[0];
  const float* emb  = (const float*)d_in[1];
  const float* W_ih = (const float*)d_in[2];
  const float* W_hh = (const float*)d_in[3];
  const float* b_ih = (const float*)d_in[4];
  const float* b_hh = (const float*)d_in[5];
  float* out = (float*)d_out;

  unsigned short* emb_hi = (unsigned short*)d_ws;      // 16 MB
  unsigned short* emb_lo = emb_hi + 8388608;           // 16 MB
  unsigned short* hbuf   = emb_lo + 8388608;           // 512-slot ring, 32 MB

  hipLaunchKernelGGL(gather_kernel, dim3(2048), dim3(256), 0, stream,
                     x, emb, emb_hi, emb_lo, hbuf);

  void* args[] = { (void*)&emb_hi, (void*)&emb_lo, (void*)&hbuf,
                   (void*)&W_ih, (void*)&W_hh, (void*)&b_ih, (void*)&b_hh,
                   (void*)&out };
  hipLaunchCooperativeKernel((void*)lstm_kernel, dim3(256), dim3(256), args, 0, stream);
}

// Round 13
// 3611.866 us; speedup vs baseline: 2.8100x; 1.0666x over previous
//
#include <hip/hip_runtime.h>

#define Bb 32
#define Tt 512
#define Ee 512
#define Hh 1024
#define NSLOT 256

typedef __attribute__((ext_vector_type(8))) short bf16x8;
typedef __attribute__((ext_vector_type(4))) float f32x4;
typedef __attribute__((ext_vector_type(4))) unsigned u32x4;
typedef unsigned long long u64;

__device__ __forceinline__ unsigned short f2bf(float f) {
  unsigned int u = __float_as_uint(f);
  u = (u + 0x7fffu + ((u >> 16) & 1u)) >> 16;
  return (unsigned short)u;
}
__device__ __forceinline__ float bf2f(unsigned short s) {
  return __uint_as_float(((unsigned int)s) << 16);
}
__device__ __forceinline__ float sigmoidf_(float x) {
  x = fminf(fmaxf(x, -30.f), 30.f);
  return 1.f / (1.f + __expf(-x));
}
__device__ __forceinline__ float tanh_fast(float x) {
  float xx = fminf(fmaxf(x, -15.f), 15.f);
  float e = __expf(2.f * xx);
  return (e - 1.f) / (e + 1.f);
}

// K1: gather embedding rows -> bf16 hi/lo; zero h ring slot 0 + flag state.
__global__ void gather_kernel(const int* __restrict__ x,
                              const float* __restrict__ emb,
                              unsigned short* __restrict__ emb_hi,
                              unsigned short* __restrict__ emb_lo,
                              unsigned short* __restrict__ hbuf,
                              unsigned* __restrict__ bar) {
  long long gid = (long long)blockIdx.x * blockDim.x + threadIdx.x;
  long long stride = (long long)gridDim.x * blockDim.x;
  for (long long i = gid; i < 8192; i += stride)
    ((ushort4*)hbuf)[i] = make_ushort4(0, 0, 0, 0);
  for (long long i = gid; i < 1024; i += stride)
    bar[i] = 0u;
  long long n4 = (long long)Bb * Tt * Ee / 4;
  for (long long i = gid; i < n4; i += stride) {
    long long bt = i >> 7;
    int e4 = (int)(i & 127);
    int row = x[bt];
    row = min(max(row, 0), 31999);
    float4 v = ((const float4*)(emb + (long long)row * Ee))[e4];
    ushort4 hv, lv;
    hv.x = f2bf(v.x); lv.x = f2bf(v.x - bf2f(hv.x));
    hv.y = f2bf(v.y); lv.y = f2bf(v.y - bf2f(hv.y));
    hv.z = f2bf(v.z); lv.z = f2bf(v.z - bf2f(hv.z));
    hv.w = f2bf(v.w); lv.w = f2bf(v.w - bf2f(hv.w));
    ((ushort4*)emb_hi)[i] = hv;
    ((ushort4*)emb_lo)[i] = lv;
  }
}

// K2: persistent LSTM, R9 structure. Flags: 512 plain u32 slots (2 KB);
// slot 2*wg+wv is STORE-once-per-step (sc1, post-drain) — zero RMWs.
// Consumers: every wave polls all 512 flags via 2x global_load_dwordx4
// sc0 sc1 per lane (one LLC RTT per iteration), tight spin, no sleep.
// h: 256-slot cold ring, plain L2-amplified loads (R9-proven).
__global__ __launch_bounds__(256, 1)
void lstm_kernel(const unsigned short* __restrict__ emb_hi,
                 const unsigned short* __restrict__ emb_lo,
                 unsigned short* __restrict__ hbuf,
                 unsigned* __restrict__ bar,
                 const float* __restrict__ W_ih,
                 const float* __restrict__ W_hh,
                 const float* __restrict__ b_ih,
                 const float* __restrict__ b_hh,
                 float* __restrict__ out) {
  __shared__ unsigned short sWih_hi[16 * 512];
  __shared__ unsigned short sWih_lo[16 * 512];
  __shared__ unsigned short sWhh_hi[16 * 1024];
  __shared__ unsigned short sWhh_lo[16 * 1024];
  __shared__ float sAcc[2][4][2][16][17];
  __shared__ float sBias[16];
  __shared__ float sC[32][4];

  const int tid = threadIdx.x;
  const int lane = tid & 63;
  const int wv = tid >> 6;
  const int wg = blockIdx.x;
  const int j0 = (wg & 7) * 128 + (wg >> 3) * 4;

  // ---- stage W_ih slice (16 rows x 512) hi/lo bf16, XOR-swizzled ----
  for (int idx = tid; idx < 16 * 64; idx += 256) {
    int c = idx >> 6, kc8 = idx & 63;
    int grow = (c >> 2) * Hh + j0 + (c & 3);
    const float* src = W_ih + (long long)grow * Ee + kc8 * 8;
    int us = (c * 512 + kc8 * 8) ^ ((c & 7) << 3);
#pragma unroll
    for (int j = 0; j < 8; j++) {
      float f = src[j];
      unsigned short h = f2bf(f);
      sWih_hi[us + j] = h;
      sWih_lo[us + j] = f2bf(f - bf2f(h));
    }
  }
  // ---- stage W_hh slice (16 rows x 1024) ----
  for (int idx = tid; idx < 16 * 128; idx += 256) {
    int c = idx >> 7, kc8 = idx & 127;
    int grow = (c >> 2) * Hh + j0 + (c & 3);
    const float* src = W_hh + (long long)grow * Hh + kc8 * 8;
    int us = (c * 1024 + kc8 * 8) ^ ((c & 7) << 3);
#pragma unroll
    for (int j = 0; j < 8; j++) {
      float f = src[j];
      unsigned short h = f2bf(f);
      sWhh_hi[us + j] = h;
      sWhh_lo[us + j] = f2bf(f - bf2f(h));
    }
  }
  if (tid < 16) {
    int grow = (tid >> 2) * Hh + j0 + (tid & 3);
    sBias[tid] = b_ih[grow] + b_hh[grow];
  }
  if (tid < 128) sC[tid >> 2][tid & 3] = 0.f;
  __syncthreads();

  const int r16 = lane & 15;        // A-frag row (batch)
  const int kg = (lane >> 4) * 8;   // k-offset in 32-chunk
  const int col = lane & 15;        // B-frag col = gate-slice row
  const int xr = (col & 7) << 3;    // LDS swizzle

  const unsigned* fbase = bar + (lane << 3);   // this lane's 8 flags

  float h_last = 0.f, c_last = 0.f;

  for (int t = 0; t < Tt; t++) {
    f32x4 acc[2][3];
#pragma unroll
    for (int mt = 0; mt < 2; mt++)
#pragma unroll
      for (int cb = 0; cb < 3; cb++)
        acc[mt][cb] = (f32x4){0.f, 0.f, 0.f, 0.f};

    // ---- x_proj contribution (independent of h; overlaps flag wait) ----
#pragma unroll
    for (int q = 0; q < 4; q++) {
      int kc = wv + q * 4;
      int bo = (col * 512 + kc * 32 + kg) ^ xr;
      bf16x8 bH = *(const bf16x8*)(sWih_hi + bo);
      bf16x8 bL = *(const bf16x8*)(sWih_lo + bo);
#pragma unroll
      for (int mt = 0; mt < 2; mt++) {
        int rb = mt * 16 + r16;
        int ai = (rb * Tt + t) * Ee + kc * 32 + kg;
        bf16x8 aH = *(const bf16x8*)(emb_hi + ai);
        bf16x8 aL = *(const bf16x8*)(emb_lo + ai);
        acc[mt][0] = __builtin_amdgcn_mfma_f32_16x16x32_bf16(aH, bH, acc[mt][0], 0, 0, 0);
        acc[mt][1] = __builtin_amdgcn_mfma_f32_16x16x32_bf16(aH, bL, acc[mt][1], 0, 0, 0);
        acc[mt][2] = __builtin_amdgcn_mfma_f32_16x16x32_bf16(aL, bH, acc[mt][2], 0, 0, 0);
      }
    }

    // ---- per-wave wait: all 512 store-flags >= t (8 flags per lane) ----
    {
      unsigned tgt = (unsigned)t;
      for (;;) {
        u32x4 f0, f1;
        asm volatile(
            "global_load_dwordx4 %0, %2, off sc0 sc1\n\t"
            "global_load_dwordx4 %1, %2, off offset:16 sc0 sc1\n\t"
            "s_waitcnt vmcnt(0)"
            : "=&v"(f0), "=&v"(f1) : "v"(fbase) : "memory");
        bool bad = (f0[0] < tgt) | (f0[1] < tgt) | (f0[2] < tgt) | (f0[3] < tgt) |
                   (f1[0] < tgt) | (f1[1] < tgt) | (f1[2] < tgt) | (f1[3] < tgt);
        if (!__any(bad)) break;
      }
    }
    __builtin_amdgcn_sched_barrier(0);   // keep h loads below the poll

    // ---- recurrent contribution: PLAIN loads from cold ring slot ----
    const unsigned short* hb = hbuf + (unsigned)(t & (NSLOT - 1)) * 32768;
#pragma unroll
    for (int q = 0; q < 8; q++) {
      int kc = wv + q * 4;
      int bo = (col * 1024 + kc * 32 + kg) ^ xr;
      bf16x8 bH = *(const bf16x8*)(sWhh_hi + bo);
      bf16x8 bL = *(const bf16x8*)(sWhh_lo + bo);
#pragma unroll
      for (int mt = 0; mt < 2; mt++) {
        int rb = mt * 16 + r16;
        bf16x8 aH = *(const bf16x8*)(hb + rb * Hh + kc * 32 + kg);
        acc[mt][0] = __builtin_amdgcn_mfma_f32_16x16x32_bf16(aH, bH, acc[mt][0], 0, 0, 0);
        acc[mt][1] = __builtin_amdgcn_mfma_f32_16x16x32_bf16(aH, bL, acc[mt][1], 0, 0, 0);
      }
    }

    // ---- cross-wave K-split reduction via LDS (parity-double-buffered) ----
#pragma unroll
    for (int mt = 0; mt < 2; mt++) {
      f32x4 tot = acc[mt][0] + acc[mt][1] + acc[mt][2];
#pragma unroll
      for (int r = 0; r < 4; r++)
        sAcc[t & 1][wv][mt][(lane >> 4) * 4 + r][col] = tot[r];
    }
    __syncthreads();

    if (tid < 128) {
      int b = tid >> 2, du = tid & 3;
      int mt = b >> 4, rr = b & 15;
      float g0 = sBias[0 * 4 + du], g1 = sBias[1 * 4 + du];
      float g2 = sBias[2 * 4 + du], g3 = sBias[3 * 4 + du];
#pragma unroll
      for (int w = 0; w < 4; w++) {
        g0 += sAcc[t & 1][w][mt][rr][0 * 4 + du];
        g1 += sAcc[t & 1][w][mt][rr][1 * 4 + du];
        g2 += sAcc[t & 1][w][mt][rr][2 * 4 + du];
        g3 += sAcc[t & 1][w][mt][rr][3 * 4 + du];
      }
      float ig = sigmoidf_(g0);
      float fg = sigmoidf_(g1);
      float gg = tanh_fast(g2);
      float og = sigmoidf_(g3);
      float cn = fg * sC[b][du] + ig * gg;
      sC[b][du] = cn;
      float hn = og * tanh_fast(cn);
      h_last = hn; c_last = cn;

      // publish h (single bf16) into ring slot t+1 via sc1 u32 stores
      unsigned pack = (unsigned)f2bf(hn);
      unsigned other = __shfl_xor(pack, 1, 64);
      unsigned* nb32 =
          (unsigned*)(hbuf + (unsigned)((t + 1) & (NSLOT - 1)) * 32768);
      if ((du & 1) == 0) {
        unsigned w = (pack & 0xffffu) | (other << 16);
        __hip_atomic_store(nb32 + ((b * 1024 + j0 + du) >> 1), w,
                           __ATOMIC_RELAXED, __HIP_MEMORY_SCOPE_AGENT);
      }
      // per-cell-wave drain, then ONE plain sc1 flag STORE per wave (no RMW)
      asm volatile("s_waitcnt vmcnt(0)" ::: "memory");
      if ((tid & 63) == 0)
        __hip_atomic_store(bar + wg * 2 + (tid >> 6), (unsigned)(t + 1),
                           __ATOMIC_RELAXED, __HIP_MEMORY_SCOPE_AGENT);
      out[((long long)b * Tt + t) * Hh + j0 + du] = hn;
    }
    // no tail barrier: sAcc parity-buffered; ring reuse distance = 256 steps
  }

  if (tid < 128) {
    int b = tid >> 2, du = tid & 3;
    int hj = j0 + du;
    out[16777216LL + b * Hh + hj] = h_last;           // state_h
    out[16777216LL + 32768 + b * Hh + hj] = c_last;   // state_c
  }
}

extern "C" void kernel_launch(void* const* d_in, const int* in_sizes, int n_in,
                              void* d_out, int out_size, void* d_ws, size_t ws_size,
                              hipStream_t stream) {
  const int* x      = (const int*)d_in[0];
  const float* emb  = (const float*)d_in[1];
  const float* W_ih = (const float*)d_in[2];
  const float* W_hh = (const float*)d_in[3];
  const float* b_ih = (const float*)d_in[4];
  const float* b_hh = (const float*)d_in[5];
  float* out = (float*)d_out;

  unsigned short* emb_hi = (unsigned short*)d_ws;      // 16 MB
  unsigned short* emb_lo = emb_hi + 8388608;           // 16 MB
  unsigned short* hbuf   = emb_lo + 8388608;           // 256-slot ring, 16 MB
  unsigned*       bar    = (unsigned*)(hbuf + 8388608); // 4 KB flag state

  hipLaunchKernelGGL(gather_kernel, dim3(2048), dim3(256), 0, stream,
                     x, emb, emb_hi, emb_lo, hbuf, bar);

  void* args[] = { (void*)&emb_hi, (void*)&emb_lo, (void*)&hbuf, (void*)&bar,
                   (void*)&W_ih, (void*)&W_hh, (void*)&b_ih, (void*)&b_hh,
                   (void*)&out };
  hipLaunchCooperativeKernel((void*)lstm_kernel, dim3(256), dim3(256), args, 0, stream);
}

// Round 14
// 3459.478 us; speedup vs baseline: 2.9338x; 1.0440x over previous
//
#include <hip/hip_runtime.h>

#define Bb 32
#define Tt 512
#define Ee 512
#define Hh 1024
#define NSLOT 256

typedef __attribute__((ext_vector_type(8))) short bf16x8;
typedef __attribute__((ext_vector_type(4))) float f32x4;
typedef unsigned long long u64;

__device__ __forceinline__ unsigned short f2bf(float f) {
  unsigned int u = __float_as_uint(f);
  u = (u + 0x7fffu + ((u >> 16) & 1u)) >> 16;
  return (unsigned short)u;
}
__device__ __forceinline__ float bf2f(unsigned short s) {
  return __uint_as_float(((unsigned int)s) << 16);
}
__device__ __forceinline__ float sigmoidf_(float x) {
  x = fminf(fmaxf(x, -30.f), 30.f);
  return 1.f / (1.f + __expf(-x));
}
__device__ __forceinline__ float tanh_fast(float x) {
  float xx = fminf(fmaxf(x, -15.f), 15.f);
  float e = __expf(2.f * xx);
  return (e - 1.f) / (e + 1.f);
}

// K1: gather embedding rows -> bf16 hi/lo; zero h ring slot 0 + flag state.
__global__ void gather_kernel(const int* __restrict__ x,
                              const float* __restrict__ emb,
                              unsigned short* __restrict__ emb_hi,
                              unsigned short* __restrict__ emb_lo,
                              unsigned short* __restrict__ hbuf,
                              unsigned* __restrict__ bar) {
  long long gid = (long long)blockIdx.x * blockDim.x + threadIdx.x;
  long long stride = (long long)gridDim.x * blockDim.x;
  for (long long i = gid; i < 8192; i += stride)
    ((ushort4*)hbuf)[i] = make_ushort4(0, 0, 0, 0);
  for (long long i = gid; i < 1024; i += stride)
    bar[i] = 0u;
  long long n4 = (long long)Bb * Tt * Ee / 4;
  for (long long i = gid; i < n4; i += stride) {
    long long bt = i >> 7;
    int e4 = (int)(i & 127);
    int row = x[bt];
    row = min(max(row, 0), 31999);
    float4 v = ((const float4*)(emb + (long long)row * Ee))[e4];
    ushort4 hv, lv;
    hv.x = f2bf(v.x); lv.x = f2bf(v.x - bf2f(hv.x));
    hv.y = f2bf(v.y); lv.y = f2bf(v.y - bf2f(hv.y));
    hv.z = f2bf(v.z); lv.z = f2bf(v.z - bf2f(hv.z));
    hv.w = f2bf(v.w); lv.w = f2bf(v.w - bf2f(hv.w));
    ((ushort4*)emb_hi)[i] = hv;
    ((ushort4*)emb_lo)[i] = lv;
  }
}

// K1b: precompute xp[t][b][grow] = W_ih · emb  (hi/lo split, f32 out).
// 64 WGs; WG p owns 64 gate rows: grow = g*1024 + p*16 + u (g=ct, u=0..15).
// Per wave: gate-tile ct=wv, full K=512, both batch-tiles — no reduce needed.
__global__ __launch_bounds__(256, 1)
void xproj_kernel(const unsigned short* __restrict__ emb_hi,
                  const unsigned short* __restrict__ emb_lo,
                  const float* __restrict__ W_ih,
                  float* __restrict__ xp) {
  __shared__ unsigned short sW_hi[64 * 512];
  __shared__ unsigned short sW_lo[64 * 512];
  const int tid = threadIdx.x;
  const int lane = tid & 63;
  const int wv = tid >> 6;
  const int p = blockIdx.x;

  for (int idx = tid; idx < 64 * 64; idx += 256) {
    int c = idx >> 6, k8 = idx & 63;
    int grow = (c >> 4) * Hh + p * 16 + (c & 15);
    const float* src = W_ih + (long long)grow * Ee + k8 * 8;
    int us = (c * 512 + k8 * 8) ^ ((c & 7) << 3);
#pragma unroll
    for (int j = 0; j < 8; j++) {
      float f = src[j];
      unsigned short h = f2bf(f);
      sW_hi[us + j] = h;
      sW_lo[us + j] = f2bf(f - bf2f(h));
    }
  }
  __syncthreads();

  const int r16 = lane & 15;
  const int kg = (lane >> 4) * 8;
  const int cB = wv * 16 + (lane & 15);   // this wave's B-frag col
  const int xrB = (cB & 7) << 3;
  const int growc = wv * Hh + p * 16 + (lane & 15);

  for (int t = 0; t < Tt; t++) {
    f32x4 acc[2][3];
#pragma unroll
    for (int mt = 0; mt < 2; mt++)
#pragma unroll
      for (int cb = 0; cb < 3; cb++)
        acc[mt][cb] = (f32x4){0.f, 0.f, 0.f, 0.f};
#pragma unroll
    for (int q = 0; q < 16; q++) {
      int bo = (cB * 512 + q * 32 + kg) ^ xrB;
      bf16x8 bH = *(const bf16x8*)(sW_hi + bo);
      bf16x8 bL = *(const bf16x8*)(sW_lo + bo);
#pragma unroll
      for (int mt = 0; mt < 2; mt++) {
        long long ai = ((long long)(mt * 16 + r16) * Tt + t) * Ee + q * 32 + kg;
        bf16x8 aH = *(const bf16x8*)(emb_hi + ai);
        bf16x8 aL = *(const bf16x8*)(emb_lo + ai);
        acc[mt][0] = __builtin_amdgcn_mfma_f32_16x16x32_bf16(aH, bH, acc[mt][0], 0, 0, 0);
        acc[mt][1] = __builtin_amdgcn_mfma_f32_16x16x32_bf16(aH, bL, acc[mt][1], 0, 0, 0);
        acc[mt][2] = __builtin_amdgcn_mfma_f32_16x16x32_bf16(aL, bH, acc[mt][2], 0, 0, 0);
      }
    }
#pragma unroll
    for (int mt = 0; mt < 2; mt++) {
      f32x4 v = acc[mt][0] + acc[mt][1] + acc[mt][2];
#pragma unroll
      for (int r = 0; r < 4; r++) {
        int b = (lane >> 4) * 4 + r + 16 * mt;
        xp[((long long)t * Bb + b) * 4096 + growc] = v[r];
      }
    }
  }
}

// K2 (main): persistent LSTM, R9 protocol, x_proj via precomputed xp.
__global__ __launch_bounds__(256, 1)
void lstm_kernel(const unsigned short* __restrict__ hbuf_c,
                 unsigned* __restrict__ bar,
                 const float* __restrict__ xp,
                 const float* __restrict__ W_hh,
                 const float* __restrict__ b_ih,
                 const float* __restrict__ b_hh,
                 float* __restrict__ out) {
  __shared__ unsigned short sWhh_hi[16 * 1024];
  __shared__ unsigned short sWhh_lo[16 * 1024];
  __shared__ float sAcc[2][4][2][16][17];
  __shared__ float sBias[16];
  __shared__ float sC[32][4];

  unsigned short* hbuf = (unsigned short*)hbuf_c;
  const int tid = threadIdx.x;
  const int lane = tid & 63;
  const int wv = tid >> 6;
  const int wg = blockIdx.x;
  const int j0 = (wg & 7) * 128 + (wg >> 3) * 4;
  const int gflag = (wg & 7) * 4 + (wg >> 6);

  for (int idx = tid; idx < 16 * 128; idx += 256) {
    int c = idx >> 7, kc8 = idx & 127;
    int grow = (c >> 2) * Hh + j0 + (c & 3);
    const float* src = W_hh + (long long)grow * Hh + kc8 * 8;
    int us = (c * 1024 + kc8 * 8) ^ ((c & 7) << 3);
#pragma unroll
    for (int j = 0; j < 8; j++) {
      float f = src[j];
      unsigned short h = f2bf(f);
      sWhh_hi[us + j] = h;
      sWhh_lo[us + j] = f2bf(f - bf2f(h));
    }
  }
  if (tid < 16) {
    int grow = (tid >> 2) * Hh + j0 + (tid & 3);
    sBias[tid] = b_ih[grow] + b_hh[grow];
  }
  if (tid < 128) sC[tid >> 2][tid & 3] = 0.f;
  __syncthreads();

  const int r16 = lane & 15;
  const int kg = (lane >> 4) * 8;
  const int col = lane & 15;
  const int xr = (col & 7) << 3;
  const unsigned* fp = bar + (unsigned)(wv + 4 * (lane & 7)) * 16;

  float h_last = 0.f, c_last = 0.f;

  for (int t = 0; t < Tt; t++) {
    // prefetch this thread's xp gates (independent of h; hides under wait)
    float xg0 = 0.f, xg1 = 0.f, xg2 = 0.f, xg3 = 0.f;
    if (tid < 128) {
      int b = tid >> 2, du = tid & 3;
      const float* xb = xp + ((long long)t * Bb + b) * 4096 + j0 + du;
      xg0 = xb[0]; xg1 = xb[1024]; xg2 = xb[2048]; xg3 = xb[3072];
    }

    // per-wave wait: this wave's 8 K-groups published for step t
    {
      unsigned target = 16u * (unsigned)t;
      while (__any(__hip_atomic_load(fp, __ATOMIC_RELAXED,
                                     __HIP_MEMORY_SCOPE_AGENT) < target))
        __builtin_amdgcn_s_sleep(1);
    }
    __builtin_amdgcn_sched_barrier(0);

    // recurrent contribution: PLAIN loads from cold ring slot
    const unsigned short* hb = hbuf + (unsigned)(t & (NSLOT - 1)) * 32768;
    f32x4 acc[2][2];
#pragma unroll
    for (int mt = 0; mt < 2; mt++)
#pragma unroll
      for (int cb = 0; cb < 2; cb++)
        acc[mt][cb] = (f32x4){0.f, 0.f, 0.f, 0.f};
#pragma unroll
    for (int q = 0; q < 8; q++) {
      int kc = wv + q * 4;
      int bo = (col * 1024 + kc * 32 + kg) ^ xr;
      bf16x8 bH = *(const bf16x8*)(sWhh_hi + bo);
      bf16x8 bL = *(const bf16x8*)(sWhh_lo + bo);
#pragma unroll
      for (int mt = 0; mt < 2; mt++) {
        int rb = mt * 16 + r16;
        bf16x8 aH = *(const bf16x8*)(hb + rb * Hh + kc * 32 + kg);
        acc[mt][0] = __builtin_amdgcn_mfma_f32_16x16x32_bf16(aH, bH, acc[mt][0], 0, 0, 0);
        acc[mt][1] = __builtin_amdgcn_mfma_f32_16x16x32_bf16(aH, bL, acc[mt][1], 0, 0, 0);
      }
    }

#pragma unroll
    for (int mt = 0; mt < 2; mt++) {
      f32x4 tot = acc[mt][0] + acc[mt][1];
#pragma unroll
      for (int r = 0; r < 4; r++)
        sAcc[t & 1][wv][mt][(lane >> 4) * 4 + r][col] = tot[r];
    }
    __syncthreads();

    if (tid < 128) {
      int b = tid >> 2, du = tid & 3;
      int mt = b >> 4, rr = b & 15;
      float g0 = sBias[0 * 4 + du] + xg0, g1 = sBias[1 * 4 + du] + xg1;
      float g2 = sBias[2 * 4 + du] + xg2, g3 = sBias[3 * 4 + du] + xg3;
#pragma unroll
      for (int w = 0; w < 4; w++) {
        g0 += sAcc[t & 1][w][mt][rr][0 * 4 + du];
        g1 += sAcc[t & 1][w][mt][rr][1 * 4 + du];
        g2 += sAcc[t & 1][w][mt][rr][2 * 4 + du];
        g3 += sAcc[t & 1][w][mt][rr][3 * 4 + du];
      }
      float ig = sigmoidf_(g0);
      float fg = sigmoidf_(g1);
      float gg = tanh_fast(g2);
      float og = sigmoidf_(g3);
      float cn = fg * sC[b][du] + ig * gg;
      sC[b][du] = cn;
      float hn = og * tanh_fast(cn);
      h_last = hn; c_last = cn;

      unsigned pack = (unsigned)f2bf(hn);
      unsigned other = __shfl_xor(pack, 1, 64);
      unsigned* nb32 =
          (unsigned*)(hbuf + (unsigned)((t + 1) & (NSLOT - 1)) * 32768);
      if ((du & 1) == 0) {
        unsigned w = (pack & 0xffffu) | (other << 16);
        __hip_atomic_store(nb32 + ((b * 1024 + j0 + du) >> 1), w,
                           __ATOMIC_RELAXED, __HIP_MEMORY_SCOPE_AGENT);
      }
      asm volatile("s_waitcnt vmcnt(0)" ::: "memory");
      if ((tid & 63) == 0)
        __hip_atomic_fetch_add(bar + gflag * 16, 1u, __ATOMIC_RELAXED,
                               __HIP_MEMORY_SCOPE_AGENT);
      out[((long long)b * Tt + t) * Hh + j0 + du] = hn;
    }
  }

  if (tid < 128) {
    int b = tid >> 2, du = tid & 3;
    int hj = j0 + du;
    out[16777216LL + b * Hh + hj] = h_last;
    out[16777216LL + 32768 + b * Hh + hj] = c_last;
  }
}

// ---------------- R9 fallback (ws too small for xp) ----------------
__global__ __launch_bounds__(256, 1)
void lstm_kernel_fb(const unsigned short* __restrict__ emb_hi,
                    const unsigned short* __restrict__ emb_lo,
                    unsigned short* __restrict__ hbuf,
                    unsigned* __restrict__ bar,
                    const float* __restrict__ W_ih,
                    const float* __restrict__ W_hh,
                    const float* __restrict__ b_ih,
                    const float* __restrict__ b_hh,
                    float* __restrict__ out) {
  __shared__ unsigned short sWih_hi[16 * 512];
  __shared__ unsigned short sWih_lo[16 * 512];
  __shared__ unsigned short sWhh_hi[16 * 1024];
  __shared__ unsigned short sWhh_lo[16 * 1024];
  __shared__ float sAcc[2][4][2][16][17];
  __shared__ float sBias[16];
  __shared__ float sC[32][4];

  const int tid = threadIdx.x;
  const int lane = tid & 63;
  const int wv = tid >> 6;
  const int wg = blockIdx.x;
  const int j0 = (wg & 7) * 128 + (wg >> 3) * 4;
  const int gflag = (wg & 7) * 4 + (wg >> 6);

  for (int idx = tid; idx < 16 * 64; idx += 256) {
    int c = idx >> 6, kc8 = idx & 63;
    int grow = (c >> 2) * Hh + j0 + (c & 3);
    const float* src = W_ih + (long long)grow * Ee + kc8 * 8;
    int us = (c * 512 + kc8 * 8) ^ ((c & 7) << 3);
#pragma unroll
    for (int j = 0; j < 8; j++) {
      float f = src[j];
      unsigned short h = f2bf(f);
      sWih_hi[us + j] = h;
      sWih_lo[us + j] = f2bf(f - bf2f(h));
    }
  }
  for (int idx = tid; idx < 16 * 128; idx += 256) {
    int c = idx >> 7, kc8 = idx & 127;
    int grow = (c >> 2) * Hh + j0 + (c & 3);
    const float* src = W_hh + (long long)grow * Hh + kc8 * 8;
    int us = (c * 1024 + kc8 * 8) ^ ((c & 7) << 3);
#pragma unroll
    for (int j = 0; j < 8; j++) {
      float f = src[j];
      unsigned short h = f2bf(f);
      sWhh_hi[us + j] = h;
      sWhh_lo[us + j] = f2bf(f - bf2f(h));
    }
  }
  if (tid < 16) {
    int grow = (tid >> 2) * Hh + j0 + (tid & 3);
    sBias[tid] = b_ih[grow] + b_hh[grow];
  }
  if (tid < 128) sC[tid >> 2][tid & 3] = 0.f;
  __syncthreads();

  const int r16 = lane & 15;
  const int kg = (lane >> 4) * 8;
  const int col = lane & 15;
  const int xr = (col & 7) << 3;
  const unsigned* fp = bar + (unsigned)(wv + 4 * (lane & 7)) * 16;

  float h_last = 0.f, c_last = 0.f;

  for (int t = 0; t < Tt; t++) {
    f32x4 acc[2][3];
#pragma unroll
    for (int mt = 0; mt < 2; mt++)
#pragma unroll
      for (int cb = 0; cb < 3; cb++)
        acc[mt][cb] = (f32x4){0.f, 0.f, 0.f, 0.f};
#pragma unroll
    for (int q = 0; q < 4; q++) {
      int kc = wv + q * 4;
      int bo = (col * 512 + kc * 32 + kg) ^ xr;
      bf16x8 bH = *(const bf16x8*)(sWih_hi + bo);
      bf16x8 bL = *(const bf16x8*)(sWih_lo + bo);
#pragma unroll
      for (int mt = 0; mt < 2; mt++) {
        int rb = mt * 16 + r16;
        int ai = (rb * Tt + t) * Ee + kc * 32 + kg;
        bf16x8 aH = *(const bf16x8*)(emb_hi + ai);
        bf16x8 aL = *(const bf16x8*)(emb_lo + ai);
        acc[mt][0] = __builtin_amdgcn_mfma_f32_16x16x32_bf16(aH, bH, acc[mt][0], 0, 0, 0);
        acc[mt][1] = __builtin_amdgcn_mfma_f32_16x16x32_bf16(aH, bL, acc[mt][1], 0, 0, 0);
        acc[mt][2] = __builtin_amdgcn_mfma_f32_16x16x32_bf16(aL, bH, acc[mt][2], 0, 0, 0);
      }
    }
    {
      unsigned target = 16u * (unsigned)t;
      while (__any(__hip_atomic_load(fp, __ATOMIC_RELAXED,
                                     __HIP_MEMORY_SCOPE_AGENT) < target))
        __builtin_amdgcn_s_sleep(1);
    }
    __builtin_amdgcn_sched_barrier(0);
    const unsigned short* hb = hbuf + (unsigned)(t & (NSLOT - 1)) * 32768;
#pragma unroll
    for (int q = 0; q < 8; q++) {
      int kc = wv + q * 4;
      int bo = (col * 1024 + kc * 32 + kg) ^ xr;
      bf16x8 bH = *(const bf16x8*)(sWhh_hi + bo);
      bf16x8 bL = *(const bf16x8*)(sWhh_lo + bo);
#pragma unroll
      for (int mt = 0; mt < 2; mt++) {
        int rb = mt * 16 + r16;
        bf16x8 aH = *(const bf16x8*)(hb + rb * Hh + kc * 32 + kg);
        acc[mt][0] = __builtin_amdgcn_mfma_f32_16x16x32_bf16(aH, bH, acc[mt][0], 0, 0, 0);
        acc[mt][1] = __builtin_amdgcn_mfma_f32_16x16x32_bf16(aH, bL, acc[mt][1], 0, 0, 0);
      }
    }
#pragma unroll
    for (int mt = 0; mt < 2; mt++) {
      f32x4 tot = acc[mt][0] + acc[mt][1] + acc[mt][2];
#pragma unroll
      for (int r = 0; r < 4; r++)
        sAcc[t & 1][wv][mt][(lane >> 4) * 4 + r][col] = tot[r];
    }
    __syncthreads();
    if (tid < 128) {
      int b = tid >> 2, du = tid & 3;
      int mt = b >> 4, rr = b & 15;
      float g0 = sBias[0 * 4 + du], g1 = sBias[1 * 4 + du];
      float g2 = sBias[2 * 4 + du], g3 = sBias[3 * 4 + du];
#pragma unroll
      for (int w = 0; w < 4; w++) {
        g0 += sAcc[t & 1][w][mt][rr][0 * 4 + du];
        g1 += sAcc[t & 1][w][mt][rr][1 * 4 + du];
        g2 += sAcc[t & 1][w][mt][rr][2 * 4 + du];
        g3 += sAcc[t & 1][w][mt][rr][3 * 4 + du];
      }
      float ig = sigmoidf_(g0);
      float fg = sigmoidf_(g1);
      float gg = tanh_fast(g2);
      float og = sigmoidf_(g3);
      float cn = fg * sC[b][du] + ig * gg;
      sC[b][du] = cn;
      float hn = og * tanh_fast(cn);
      h_last = hn; c_last = cn;
      unsigned pack = (unsigned)f2bf(hn);
      unsigned other = __shfl_xor(pack, 1, 64);
      unsigned* nb32 =
          (unsigned*)(hbuf + (unsigned)((t + 1) & (NSLOT - 1)) * 32768);
      if ((du & 1) == 0) {
        unsigned w = (pack & 0xffffu) | (other << 16);
        __hip_atomic_store(nb32 + ((b * 1024 + j0 + du) >> 1), w,
                           __ATOMIC_RELAXED, __HIP_MEMORY_SCOPE_AGENT);
      }
      asm volatile("s_waitcnt vmcnt(0)" ::: "memory");
      if ((tid & 63) == 0)
        __hip_atomic_fetch_add(bar + gflag * 16, 1u, __ATOMIC_RELAXED,
                               __HIP_MEMORY_SCOPE_AGENT);
      out[((long long)b * Tt + t) * Hh + j0 + du] = hn;
    }
  }
  if (tid < 128) {
    int b = tid >> 2, du = tid & 3;
    int hj = j0 + du;
    out[16777216LL + b * Hh + hj] = h_last;
    out[16777216LL + 32768 + b * Hh + hj] = c_last;
  }
}

extern "C" void kernel_launch(void* const* d_in, const int* in_sizes, int n_in,
                              void* d_out, int out_size, void* d_ws, size_t ws_size,
                              hipStream_t stream) {
  const int* x      = (const int*)d_in[0];
  const float* emb  = (const float*)d_in[1];
  const float* W_ih = (const float*)d_in[2];
  const float* W_hh = (const float*)d_in[3];
  const float* b_ih = (const float*)d_in[4];
  const float* b_hh = (const float*)d_in[5];
  float* out = (float*)d_out;

  unsigned short* emb_hi = (unsigned short*)d_ws;        // 16 MB
  unsigned short* emb_lo = emb_hi + 8388608;             // 16 MB
  unsigned short* hbuf   = emb_lo + 8388608;             // 256-slot ring, 16 MB
  unsigned*       bar    = (unsigned*)(hbuf + 8388608);  // 4 KB flags
  float*          xp     = (float*)((char*)d_ws + 50335744); // 256 MB

  hipLaunchKernelGGL(gather_kernel, dim3(2048), dim3(256), 0, stream,
                     x, emb, emb_hi, emb_lo, hbuf, bar);

  if (ws_size >= 318771200ull) {
    hipLaunchKernelGGL(xproj_kernel, dim3(64), dim3(256), 0, stream,
                       emb_hi, emb_lo, W_ih, xp);
    void* args[] = { (void*)&hbuf, (void*)&bar, (void*)&xp,
                     (void*)&W_hh, (void*)&b_ih, (void*)&b_hh, (void*)&out };
    hipLaunchCooperativeKernel((void*)lstm_kernel, dim3(256), dim3(256),
                               args, 0, stream);
  } else {
    void* args[] = { (void*)&emb_hi, (void*)&emb_lo, (void*)&hbuf, (void*)&bar,
                     (void*)&W_ih, (void*)&W_hh, (void*)&b_ih, (void*)&b_hh,
                     (void*)&out };
    hipLaunchCooperativeKernel((void*)lstm_kernel_fb, dim3(256), dim3(256),
                               args, 0, stream);
  }
}